// Round 6
// baseline (1208.821 us; speedup 1.0000x reference)
//
#include <hip/hip_runtime.h>

#define L_SEQ 2048
#define C_IN  64
#define HH    128
#define NSEQ  32
#define B2    64     // 2*NSEQ sequences (fwd + rev)
#define G3    384    // 3*H
#define T_TILE 128

typedef _Float16 half2_t __attribute__((ext_vector_type(2)));

// keep a value opaque + register-resident (defeats rematerialization)
#define PINU(v) asm volatile("" : "+v"(v))

__device__ __forceinline__ float fdot2u(unsigned int a, unsigned int b, float c) {
    return __builtin_amdgcn_fdot2(__builtin_bit_cast(half2_t, a),
                                  __builtin_bit_cast(half2_t, b), c, false);
}

__device__ __forceinline__ unsigned int pack_h2(float a, float b) {
    half2_t t; t.x = (_Float16)a; t.y = (_Float16)b;
    return __builtin_bit_cast(unsigned int, t);
}

// quad-perm DPP adds: cross-lane reduce within a lane-quad, pure VALU (no DS)
__device__ __forceinline__ float qadd1(float x) {   // += lane^1
    int t = __builtin_amdgcn_update_dpp(0, __builtin_bit_cast(int, x),
                                        0xB1, 0xF, 0xF, true); // [1,0,3,2]
    return x + __builtin_bit_cast(float, t);
}
__device__ __forceinline__ float qadd2(float x) {   // += lane^2
    int t = __builtin_amdgcn_update_dpp(0, __builtin_bit_cast(int, x),
                                        0x4E, 0xF, 0xF, true); // [2,3,0,1]
    return x + __builtin_bit_cast(float, t);
}

__device__ __forceinline__ float fast_sigmoid(float x) {
    float e = __builtin_amdgcn_exp2f(-1.4426950408889634f * x);
    return __builtin_amdgcn_rcpf(1.0f + e);
}

__device__ __forceinline__ float fast_tanh(float x) {
    float a = fabsf(x);
    float e = __builtin_amdgcn_exp2f(-2.8853900817779268f * a); // e^{-2a}
    float r = (1.0f - e) * __builtin_amdgcn_rcpf(1.0f + e);
    return copysignf(r, x);
}

// ---------------------------------------------------------------------------
// Kernel 1: xw[s][tt][j] = bias[j] + sum_c xb[s][t0+tt][c] * W_ih[c][j]
// bias folds b_ih + b_hh for the r,z columns (j<256); b_hh_n stays in gru
// (it is scaled by r there). x rows are block-uniform -> scalar s_load
// broadcast. waves_per_eu(2,2) raises the VGPR budget so w[64] stays
// register-resident. 384 threads, thread = output column j.
// ---------------------------------------------------------------------------
__global__ __launch_bounds__(384) __attribute__((amdgpu_waves_per_eu(2, 2)))
void xw_kernel(const float* __restrict__ x, const int* __restrict__ lengths,
               const float* __restrict__ W_ih, const float* __restrict__ b_ih,
               const float* __restrict__ b_hh,
               float* __restrict__ xw, int t0, int chunk_steps)
{
    const int tid = threadIdx.x;
    const int tilesPerSeq = chunk_steps / T_TILE;
    const int s    = blockIdx.x / tilesPerSeq;
    const int tile = blockIdx.x % tilesPerSeq;
    const int tbase = t0 + tile * T_TILE;          // global t of row 0

    const int len = (s >= NSEQ) ? lengths[s - NSEQ] : 0;

    const int j = tid;
    float w[64];
#pragma unroll
    for (int q = 0; q < 64; ++q) w[q] = W_ih[q * G3 + j];
#pragma unroll
    for (int q = 0; q < 64; ++q) PINU(w[q]);
    const float bias = b_ih[j] + ((j < 256) ? b_hh[j] : 0.f);

    const int tloc = tile * T_TILE;
    for (int r = 0; r < T_TILE; ++r) {
        const int t = tbase + r;
        float acc = bias;
        if (s < NSEQ) {
            const float* __restrict__ xrow = x + ((size_t)s * L_SEQ + t) * C_IN;
#pragma unroll
            for (int q = 0; q < 64; ++q) acc += xrow[q] * w[q];
        } else if (t < len) {
            const float* __restrict__ xrow =
                x + ((size_t)(s - NSEQ) * L_SEQ + (len - 1 - t)) * C_IN;
#pragma unroll
            for (int q = 0; q < 64; ++q) acc += xrow[q] * w[q];
        }
        xw[((size_t)s * chunk_steps + (tloc + r)) * G3 + j] = acc;
    }
}

// ---------------------------------------------------------------------------
// Kernel 2: GRU recurrence. 64 blocks (one per sequence), 512 threads.
// Thread tid: column j = tid>>2 (r,z,n gates), K-quarter p = tid&3.
// waves_per_eu(2,2) -> 256-VGPR budget: the 48 packed f16-pair weights live
// in architectural VGPRs (no AGPR spill, no remat). f16 h double-buffered in
// LDS; v_dot2_f32_f16 MACs; DPP quad-perm reduce (no DS pipe); raw s_barrier
// per step drains lgkmcnt only (out-stores + 4-deep xw prefetch in flight).
// ---------------------------------------------------------------------------
__global__ __launch_bounds__(512) __attribute__((amdgpu_waves_per_eu(2, 2)))
void gru_kernel(const float* __restrict__ xw, const float* __restrict__ W_hh,
                const float* __restrict__ b_hh, float* __restrict__ out,
                float* __restrict__ hstate, int t0, int chunk_steps)
{
    __shared__ unsigned int hbufu[2][64];   // 128 f16 per buffer
    const int s   = blockIdx.x;
    const int tid = threadIdx.x;
    const int j   = tid >> 2;     // 0..127 output column
    const int p   = tid & 3;      // K quarter: k in [32p, 32p+32)

    // packed f16-pair weights: W_hh[32p+2q .. +1][col], col in {j,128+j,256+j}
    unsigned int wr[16], wz[16], wn[16];
    const float* Wb = W_hh + (size_t)(32 * p) * G3;
#pragma unroll
    for (int q = 0; q < 16; ++q) {
        wr[q] = pack_h2(Wb[(2*q) * G3 + j],       Wb[(2*q+1) * G3 + j]);
        wz[q] = pack_h2(Wb[(2*q) * G3 + 128 + j], Wb[(2*q+1) * G3 + 128 + j]);
        wn[q] = pack_h2(Wb[(2*q) * G3 + 256 + j], Wb[(2*q+1) * G3 + 256 + j]);
    }
#pragma unroll
    for (int q = 0; q < 16; ++q) { PINU(wr[q]); PINU(wz[q]); PINU(wn[q]); }
    float bn = b_hh[256 + j];
    PINU(bn);

    float hreg = (t0 == 0) ? 0.f : hstate[s * HH + j];   // own column's h (f32)
    if (tid < HH) {
        const float hv = (t0 == 0) ? 0.f : hstate[s * HH + tid];
        ((_Float16*)&hbufu[0][0])[tid] = (_Float16)hv;
    }
    __syncthreads();

    const float* xwp = xw + (size_t)s * chunk_steps * G3;
    float cr[4], cz[4], cn[4];
#pragma unroll
    for (int u = 0; u < 4; ++u) {
        const float* qp = xwp + (size_t)u * G3;
        cr[u] = qp[j]; cz[u] = qp[128 + j]; cn[u] = qp[256 + j];
    }

    float* outbase = out + (size_t)(s % NSEQ) * L_SEQ * 256 + ((s < NSEQ) ? 0 : HH);
    int cur = 0;

    for (int t = 0; t < chunk_steps; t += 4) {
        const int tnb = (t + 4 < chunk_steps) ? (t + 4) : t;   // clamp (dead)
        float nr[4], nz[4], nn[4];
#pragma unroll
        for (int u = 0; u < 4; ++u) {
            const float* qp = xwp + (size_t)(tnb + u) * G3;
            nr[u] = qp[j]; nz[u] = qp[128 + j]; nn[u] = qp[256 + j];
        }

#pragma unroll
        for (int u = 0; u < 4; ++u) {
            float ar = 0.f, az = 0.f, an = 0.f;
            const uint4* hb = (const uint4*)&hbufu[cur][p * 16];
#pragma unroll
            for (int i = 0; i < 4; ++i) {
                const uint4 hv = hb[i];
                ar = fdot2u(hv.x, wr[4*i+0], ar); ar = fdot2u(hv.y, wr[4*i+1], ar);
                ar = fdot2u(hv.z, wr[4*i+2], ar); ar = fdot2u(hv.w, wr[4*i+3], ar);
                az = fdot2u(hv.x, wz[4*i+0], az); az = fdot2u(hv.y, wz[4*i+1], az);
                az = fdot2u(hv.z, wz[4*i+2], az); az = fdot2u(hv.w, wz[4*i+3], az);
                an = fdot2u(hv.x, wn[4*i+0], an); an = fdot2u(hv.y, wn[4*i+1], an);
                an = fdot2u(hv.z, wn[4*i+2], an); an = fdot2u(hv.w, wn[4*i+3], an);
            }
            // combine the 4 K-quarters in-register (DPP quad-perm, no DS pipe)
            ar = qadd1(ar); ar = qadd2(ar);
            az = qadd1(az); az = qadd2(az);
            an = qadd1(an); an = qadd2(an);

            // biases b_hh_r, b_hh_z are folded into cr/cz by xw_kernel
            const float r = fast_sigmoid(cr[u] + ar);
            const float z = fast_sigmoid(cz[u] + az);
            const float n = fast_tanh(cn[u] + r * (an + bn));
            const float hnew = z * (hreg - n) + n;
            hreg = hnew;

            if (p == 0) {
                ((_Float16*)&hbufu[cur ^ 1][0])[j] = (_Float16)hnew;
                outbase[(size_t)(t0 + t + u) * 256 + j] = hnew;
            }
            // raw barrier: drain LDS only (h exchange); vmcnt stays in flight
            asm volatile("s_waitcnt lgkmcnt(0)\n\ts_barrier" ::: "memory");
            cur ^= 1;
        }
#pragma unroll
        for (int u = 0; u < 4; ++u) { cr[u] = nr[u]; cz[u] = nz[u]; cn[u] = nn[u]; }
    }

    if (t0 + chunk_steps < L_SEQ && p == 0) hstate[s * HH + j] = hreg;
}

// ---------------------------------------------------------------------------
extern "C" void kernel_launch(void* const* d_in, const int* in_sizes, int n_in,
                              void* d_out, int out_size, void* d_ws, size_t ws_size,
                              hipStream_t stream) {
    const float* x       = (const float*)d_in[0];
    const int*   lengths = (const int*)  d_in[1];
    const float* W_ih    = (const float*)d_in[2];
    const float* W_hh    = (const float*)d_in[3];
    const float* b_ih    = (const float*)d_in[4];
    const float* b_hh    = (const float*)d_in[5];
    float* out = (float*)d_out;

    // ws layout: [hstate: B2*HH floats][xw chunk buffer: rest]
    float* hstate = (float*)d_ws;
    float* xw     = hstate + B2 * HH;
    const size_t per_step = (size_t)B2 * G3 * sizeof(float);       // 98304 B
    size_t avail = (ws_size > (size_t)B2 * HH * sizeof(float))
                 ? ws_size - (size_t)B2 * HH * sizeof(float) : 0;
    long long csteps = (long long)(avail / per_step);
    int chunk;
    if (csteps >= L_SEQ)       chunk = L_SEQ;                       // single pass
    else if (csteps >= T_TILE) chunk = (int)((csteps / T_TILE) * T_TILE);
    else                       chunk = T_TILE;                      // best effort

    for (int t0 = 0; t0 < L_SEQ; t0 += chunk) {
        const int steps = (L_SEQ - t0 < chunk) ? (L_SEQ - t0) : chunk;
        xw_kernel<<<dim3((steps / T_TILE) * B2), dim3(384), 0, stream>>>(
            x, lengths, W_ih, b_ih, b_hh, xw, t0, steps);
        gru_kernel<<<dim3(B2), dim3(512), 0, stream>>>(
            xw, W_hh, b_hh, out, hstate, t0, steps);
    }
}

// Round 7
// 1104.223 us; speedup vs baseline: 1.0947x; 1.0947x over previous
//
#include <hip/hip_runtime.h>

#define L_SEQ 2048
#define C_IN  64
#define HH    128
#define NSEQ  32
#define B2    64     // 2*NSEQ sequences (fwd + rev)
#define G3    384    // 3*H
#define T_TILE 128

typedef _Float16 half2_t __attribute__((ext_vector_type(2)));

// keep a value opaque + register-resident (defeats rematerialization)
#define PINU(v) asm volatile("" : "+v"(v))

__device__ __forceinline__ float fdot2u(unsigned int a, unsigned int b, float c) {
    return __builtin_amdgcn_fdot2(__builtin_bit_cast(half2_t, a),
                                  __builtin_bit_cast(half2_t, b), c, false);
}

__device__ __forceinline__ unsigned int pack_h2(float a, float b) {
    half2_t t; t.x = (_Float16)a; t.y = (_Float16)b;
    return __builtin_bit_cast(unsigned int, t);
}

// quad-perm DPP add: reduce across lane^1, pure VALU (no DS pipe)
__device__ __forceinline__ float qadd1(float x) {   // += lane^1
    int t = __builtin_amdgcn_update_dpp(0, __builtin_bit_cast(int, x),
                                        0xB1, 0xF, 0xF, true); // [1,0,3,2]
    return x + __builtin_bit_cast(float, t);
}

__device__ __forceinline__ float fast_sigmoid(float x) {
    float e = __builtin_amdgcn_exp2f(-1.4426950408889634f * x);
    return __builtin_amdgcn_rcpf(1.0f + e);
}

__device__ __forceinline__ float fast_tanh(float x) {
    float a = fabsf(x);
    float e = __builtin_amdgcn_exp2f(-2.8853900817779268f * a); // e^{-2a}
    float r = (1.0f - e) * __builtin_amdgcn_rcpf(1.0f + e);
    return copysignf(r, x);
}

// ---------------------------------------------------------------------------
// Kernel 1: xw[s][tt][j] = bias[j] + sum_c xb[s][t0+tt][c] * W_ih[c][j]
// bias folds b_ih + b_hh for the r,z columns (j<256). x rows are
// block-uniform -> s_load broadcast; branchless row addressing + unroll 4
// keeps 4 independent s_load chains in flight. 384 threads, thread = col j.
// ---------------------------------------------------------------------------
__global__ __launch_bounds__(384) __attribute__((amdgpu_waves_per_eu(2, 2)))
void xw_kernel(const float* __restrict__ x, const int* __restrict__ lengths,
               const float* __restrict__ W_ih, const float* __restrict__ b_ih,
               const float* __restrict__ b_hh,
               float* __restrict__ xw, int t0, int chunk_steps)
{
    const int tid = threadIdx.x;
    const int tilesPerSeq = chunk_steps / T_TILE;
    const int s    = blockIdx.x / tilesPerSeq;
    const int tile = blockIdx.x % tilesPerSeq;
    const int tbase = t0 + tile * T_TILE;          // global t of row 0

    const bool isFwd = (s < NSEQ);
    const int  len   = isFwd ? L_SEQ : lengths[s - NSEQ];
    const float* __restrict__ xseq = x + (size_t)(s % NSEQ) * L_SEQ * C_IN;

    const int j = tid;
    float w[64];
#pragma unroll
    for (int q = 0; q < 64; ++q) w[q] = W_ih[q * G3 + j];
#pragma unroll
    for (int q = 0; q < 64; ++q) PINU(w[q]);
    const float bias = b_ih[j] + ((j < 256) ? b_hh[j] : 0.f);

    const int tloc = tile * T_TILE;
#pragma unroll 4
    for (int r = 0; r < T_TILE; ++r) {
        const int t = tbase + r;
        const int src = isFwd ? t : (len - 1 - t);      // block-uniform
        float acc = bias;
        if (src >= 0) {                                  // valid (t < len)
            const float* __restrict__ xrow = xseq + (size_t)src * C_IN;
#pragma unroll
            for (int q = 0; q < 64; ++q) acc += xrow[q] * w[q];
        }
        xw[((size_t)s * chunk_steps + (tloc + r)) * G3 + j] = acc;
    }
}

// ---------------------------------------------------------------------------
// Kernel 2: GRU recurrence. 64 blocks (one per sequence), 256 threads =
// 4 waves = 1 wave/SIMD. Thread tid: column j = tid>>1, K-half p = tid&1.
// 96 packed f16-pair weight u32s pinned in VGPRs (waves_per_eu(1,1) ->
// 256-reg budget), f16 h double-buffered in LDS, v_dot2_f32_f16 MACs,
// ONE DPP qadd per gate, gates duplicated x2 (was x4), raw s_barrier per
// step drains lgkmcnt only (out-stores + 4-deep xw prefetch in flight).
// ---------------------------------------------------------------------------
__global__ __launch_bounds__(256) __attribute__((amdgpu_waves_per_eu(1, 1)))
void gru_kernel(const float* __restrict__ xw, const float* __restrict__ W_hh,
                const float* __restrict__ b_hh, float* __restrict__ out,
                float* __restrict__ hstate, int t0, int chunk_steps)
{
    __shared__ unsigned int hbufu[2][64];   // 128 f16 per buffer
    const int s   = blockIdx.x;
    const int tid = threadIdx.x;
    const int j   = tid >> 1;     // 0..127 output column
    const int p   = tid & 1;      // K half: k in [64p, 64p+64)

    // packed f16-pair weights: W_hh[64p+2q .. +1][col], col in {j,128+j,256+j}
    unsigned int wr[32], wz[32], wn[32];
    const float* Wb = W_hh + (size_t)(64 * p) * G3;
#pragma unroll
    for (int q = 0; q < 32; ++q) {
        wr[q] = pack_h2(Wb[(2*q) * G3 + j],       Wb[(2*q+1) * G3 + j]);
        wz[q] = pack_h2(Wb[(2*q) * G3 + 128 + j], Wb[(2*q+1) * G3 + 128 + j]);
        wn[q] = pack_h2(Wb[(2*q) * G3 + 256 + j], Wb[(2*q+1) * G3 + 256 + j]);
    }
#pragma unroll
    for (int q = 0; q < 32; ++q) { PINU(wr[q]); PINU(wz[q]); PINU(wn[q]); }
    float bn = b_hh[256 + j];
    PINU(bn);

    float hreg = (t0 == 0) ? 0.f : hstate[s * HH + j];   // own column's h (f32)
    if (tid < HH) {
        const float hv = (t0 == 0) ? 0.f : hstate[s * HH + tid];
        ((_Float16*)&hbufu[0][0])[tid] = (_Float16)hv;
    }
    __syncthreads();

    const float* xwp = xw + (size_t)s * chunk_steps * G3;
    float cr[4], cz[4], cn[4];
#pragma unroll
    for (int u = 0; u < 4; ++u) {
        const float* qp = xwp + (size_t)u * G3;
        cr[u] = qp[j]; cz[u] = qp[128 + j]; cn[u] = qp[256 + j];
    }

    float* outbase = out + (size_t)(s % NSEQ) * L_SEQ * 256 + ((s < NSEQ) ? 0 : HH);
    int cur = 0;

    for (int t = 0; t < chunk_steps; t += 4) {
        const int tnb = (t + 4 < chunk_steps) ? (t + 4) : t;   // clamp (dead)
        float nr[4], nz[4], nn[4];
#pragma unroll
        for (int u = 0; u < 4; ++u) {
            const float* qp = xwp + (size_t)(tnb + u) * G3;
            nr[u] = qp[j]; nz[u] = qp[128 + j]; nn[u] = qp[256 + j];
        }

#pragma unroll
        for (int u = 0; u < 4; ++u) {
            float ar = 0.f, az = 0.f, an = 0.f;
            const uint4* hb = (const uint4*)&hbufu[cur][p * 32];
#pragma unroll
            for (int i = 0; i < 8; ++i) {
                const uint4 hv = hb[i];
                ar = fdot2u(hv.x, wr[4*i+0], ar); ar = fdot2u(hv.y, wr[4*i+1], ar);
                ar = fdot2u(hv.z, wr[4*i+2], ar); ar = fdot2u(hv.w, wr[4*i+3], ar);
                az = fdot2u(hv.x, wz[4*i+0], az); az = fdot2u(hv.y, wz[4*i+1], az);
                az = fdot2u(hv.z, wz[4*i+2], az); az = fdot2u(hv.w, wz[4*i+3], az);
                an = fdot2u(hv.x, wn[4*i+0], an); an = fdot2u(hv.y, wn[4*i+1], an);
                an = fdot2u(hv.z, wn[4*i+2], an); an = fdot2u(hv.w, wn[4*i+3], an);
            }
            // combine the 2 K-halves in-register (single DPP add per gate)
            ar = qadd1(ar);
            az = qadd1(az);
            an = qadd1(an);

            // biases b_hh_r, b_hh_z are folded into cr/cz by xw_kernel
            const float r = fast_sigmoid(cr[u] + ar);
            const float z = fast_sigmoid(cz[u] + az);
            const float n = fast_tanh(cn[u] + r * (an + bn));
            const float hnew = z * (hreg - n) + n;
            hreg = hnew;

            if (p == 0) {
                ((_Float16*)&hbufu[cur ^ 1][0])[j] = (_Float16)hnew;
                outbase[(size_t)(t0 + t + u) * 256 + j] = hnew;
            }
            // raw barrier: drain LDS only (h exchange); vmcnt stays in flight
            asm volatile("s_waitcnt lgkmcnt(0)\n\ts_barrier" ::: "memory");
            cur ^= 1;
        }
#pragma unroll
        for (int u = 0; u < 4; ++u) { cr[u] = nr[u]; cz[u] = nz[u]; cn[u] = nn[u]; }
    }

    if (t0 + chunk_steps < L_SEQ && p == 0) hstate[s * HH + j] = hreg;
}

// ---------------------------------------------------------------------------
extern "C" void kernel_launch(void* const* d_in, const int* in_sizes, int n_in,
                              void* d_out, int out_size, void* d_ws, size_t ws_size,
                              hipStream_t stream) {
    const float* x       = (const float*)d_in[0];
    const int*   lengths = (const int*)  d_in[1];
    const float* W_ih    = (const float*)d_in[2];
    const float* W_hh    = (const float*)d_in[3];
    const float* b_ih    = (const float*)d_in[4];
    const float* b_hh    = (const float*)d_in[5];
    float* out = (float*)d_out;

    // ws layout: [hstate: B2*HH floats][xw chunk buffer: rest]
    float* hstate = (float*)d_ws;
    float* xw     = hstate + B2 * HH;
    const size_t per_step = (size_t)B2 * G3 * sizeof(float);       // 98304 B
    size_t avail = (ws_size > (size_t)B2 * HH * sizeof(float))
                 ? ws_size - (size_t)B2 * HH * sizeof(float) : 0;
    long long csteps = (long long)(avail / per_step);
    int chunk;
    if (csteps >= L_SEQ)       chunk = L_SEQ;                       // single pass
    else if (csteps >= T_TILE) chunk = (int)((csteps / T_TILE) * T_TILE);
    else                       chunk = T_TILE;                      // best effort

    for (int t0 = 0; t0 < L_SEQ; t0 += chunk) {
        const int steps = (L_SEQ - t0 < chunk) ? (L_SEQ - t0) : chunk;
        xw_kernel<<<dim3((steps / T_TILE) * B2), dim3(384), 0, stream>>>(
            x, lengths, W_ih, b_ih, b_hh, xw, t0, steps);
        gru_kernel<<<dim3(B2), dim3(256), 0, stream>>>(
            xw, W_hh, b_hh, out, hstate, t0, steps);
    }
}